// Round 7
// baseline (110.429 us; speedup 1.0000x reference)
//
#include <hip/hip_runtime.h>

#define HH 512        // sinogram height (H_IN)
#define WW 360        // angles (W_IN)
#define NB 4          // batch
#define DD 512        // output D

#define NCHUNK 12
#define ANG_PER 30                          // 360/12

// ws layout in floats
#define OFF_TAB  0                          // float2 tab[360] -> 720 floats, pad to 1024
#define OFF_RT   1024                       // radonT [4][360][512] fp32
#define OFF_FILT (1024 + NB*WW*HH)          // filt4 [360][512][4] fp32
#define OFF_PART (OFF_FILT + WW*HH*NB)      // parts [12][4][512][512] fp32
#define CHUNK_ELEMS (NB*DD*DD)

#define PAD    128
#define COLS_N 768                          // 128 pad | 512 data | 128 pad (float4 rows)

#define GLOAD_LDS16(gp, lp)                                                   \
    __builtin_amdgcn_global_load_lds(                                         \
        (const __attribute__((address_space(1))) void*)(gp),                  \
        (__attribute__((address_space(3))) void*)(lp), 16, 0, 0)

// ---------------- K0: transpose radon[n][h][w] -> radonT[n][w][h] ----------------
__global__ __launch_bounds__(256) void k_transpose(const float* __restrict__ radon,
                                                   float* __restrict__ ws) {
    __shared__ float tile[32][33];
    int n  = blockIdx.z;
    int w0 = blockIdx.x * 32, h0 = blockIdx.y * 32;
    int x = threadIdx.x, y = threadIdx.y;  // 32 x 8
    const float* rn = radon + n * (HH * WW);
#pragma unroll
    for (int r = 0; r < 32; r += 8) {
        int h = h0 + y + r, w = w0 + x;
        tile[y + r][x] = (w < WW) ? rn[h * WW + w] : 0.f;
    }
    __syncthreads();
    float* rt = ws + OFF_RT + n * (WW * HH);
#pragma unroll
    for (int r = 0; r < 32; r += 8) {
        int w = w0 + y + r, h = h0 + x;
        if (w < WW) rt[w * HH + h] = tile[x][y + r];
    }
}

// ---------------- K1: circular ramp filter + fused angle table ----------------
// filt4[w][y][n] = sum_d radonT[n][w][(257+y+d)&511] * hG[d]
__global__ __launch_bounds__(256) void k_filter(const float* __restrict__ hG,
                                                float* __restrict__ ws) {
    __shared__ float r2[NB][1024];          // r2[n][i] = col[(i+257)&511]
    int wA  = blockIdx.x;
    int tid = threadIdx.x;

    if (tid == 0) {                          // angle table (double trig, validated)
        double th = (3.14159265358979323846 / 180.0) * (0.5 * (double)wA);
        double c = cos(th), s = sin(th);
        float2 ab;
        ab.x = (float)(c * (255.5 / 256.0));
        ab.y = (float)(-s * (255.5 / 256.0));
        ((float2*)(ws + OFF_TAB))[wA] = ab;
    }

    const float* rt = ws + OFF_RT;
    for (int t = tid; t < NB * 1024; t += 256) {
        int n = t >> 10, i = t & 1023;
        r2[n][i] = rt[(n * WW + wA) * HH + ((i + 257) & 511)];
    }
    __syncthreads();

    int n = tid >> 6, lane = tid & 63, y0 = lane << 3;   // 8 consecutive y per thread
    float acc[8] = {0, 0, 0, 0, 0, 0, 0, 0};
    const float* rr = &r2[n][y0];
    float4 Wr0 = *(const float4*)(rr + 0);
    float4 Wr1 = *(const float4*)(rr + 4);
    float4 Wr2 = *(const float4*)(rr + 8);
    float4 Wr3 = *(const float4*)(rr + 12);

    for (int d = 0; d < 512; d += 8) {
        float hg[8];
#pragma unroll
        for (int q = 0; q < 8; ++q) hg[q] = hG[d + q];   // uniform -> s_load
        float wf[16] = {Wr0.x, Wr0.y, Wr0.z, Wr0.w, Wr1.x, Wr1.y, Wr1.z, Wr1.w,
                        Wr2.x, Wr2.y, Wr2.z, Wr2.w, Wr3.x, Wr3.y, Wr3.z, Wr3.w};
#pragma unroll
        for (int du = 0; du < 8; ++du)
#pragma unroll
            for (int u = 0; u < 8; ++u)
                acc[u] = fmaf(wf[du + u], hg[du], acc[u]);
        if (d < 504) {
            Wr0 = Wr2; Wr1 = Wr3;
            Wr2 = *(const float4*)(rr + d + 16);
            Wr3 = *(const float4*)(rr + d + 20);
        }
    }
    float* filt = ws + OFF_FILT;
#pragma unroll
    for (int u = 0; u < 8; ++u)
        filt[(wA * HH + y0 + u) * NB + n] = acc[u];
}

// ---------------- K2: backprojection (i-pair 3-row shared taps) ----------------
// Thread handles 4 i-pairs (i0+2p, i0+2p+1). py(i+1) = py(i) + B, B in (-1,0]
// => both pixels' lerp windows lie in rows [m, m+2], m = floor(py(i+1)).
// 3 ds_read_b128 (one addr, imm offsets) serve 2 pixels: 24B/pixel vs 32B.
__global__ __launch_bounds__(256, 6) void k_backproj(const float* __restrict__ ws,
                                                     float* __restrict__ parts) {
    __shared__ float4 cols[2][COLS_N];
    const int tid   = threadIdx.x;
    const int lane  = tid & 63;
    const int ithr  = tid >> 6;                        // 0..3
    const int j     = blockIdx.x * 64 + lane;
    const int i0    = blockIdx.y * 32 + ithr * 8;      // i = i0 + 2p + q, p<4, q<2
    const int chunk = blockIdx.z;

    {   // zero pad regions only (never overlaps DMA region)
        int b = tid >> 7, r = tid & 127;
        float4 z = make_float4(0.f, 0.f, 0.f, 0.f);
        cols[b][r]            = z;                     // low pad  [0,128)
        cols[b][PAD + HH + r] = z;                     // high pad [640,768)
    }

    const float2* tab = (const float2*)(ws + OFF_TAB);
    const float4* fd  = (const float4*)(ws + OFF_FILT);

    float acc[8][4];
#pragma unroll
    for (int u = 0; u < 8; ++u)
#pragma unroll
        for (int n = 0; n < 4; ++n) acc[u][n] = 0.f;

    float jf = (float)(j - 256);
    float ifl[4];
#pragma unroll
    for (int p = 0; p < 4; ++p) ifl[p] = (float)(i0 + 2 * p - 256);

    const int wbeg = chunk * ANG_PER;
    {   // prologue: stage angle wbeg into buf 0 (512 x 16B = 8KB)
        const float4* src = fd + (size_t)wbeg * HH;
#pragma unroll
        for (int c = 0; c < 2; ++c) {
            int idx = tid + c * 256;
            GLOAD_LDS16(src + idx, &cols[0][PAD + idx]);
        }
    }
    __syncthreads();   // drains vmcnt(0): DMA + pad zeros visible

    int cur = 0;
    for (int k = 0; k < ANG_PER; ++k) {
        const int w = wbeg + k;
        if (k + 1 < ANG_PER) {                         // stage next angle into other buf
            const float4* src = fd + (size_t)(w + 1) * HH;
            float4* dst = &cols[cur ^ 1][PAD];
#pragma unroll
            for (int c = 0; c < 2; ++c) {
                int idx = tid + c * 256;
                GLOAD_LDS16(src + idx, dst + idx);
            }
        }

        float2 ab = tab[w];
        float pybase = fmaf(ab.x, jf, 255.5f + (float)PAD);
        const float4* cb = cols[cur];
#pragma unroll
        for (int p = 0; p < 4; ++p) {
            float py0 = fmaf(ab.y, ifl[p],        pybase);   // pixel i (higher py)
            float py1 = fmaf(ab.y, ifl[p] + 1.0f, pybase);   // pixel i+1 (lower py)
            float cf1 = truncf(py1);                         // trunc == floor (py>0)
            float cf0 = truncf(py0);
            int   m   = (int)cf1;
            float fy1 = py1 - cf1;
            float fy0 = py0 - cf0;
            bool  hi  = (cf0 > cf1);                         // c0 == m+1 ?
            float w00 = 1.f - fy0;
            float a0  = hi ? 0.f : w00;
            float a1  = hi ? w00 : fy0;
            float a2  = hi ? fy0 : 0.f;
            float b0  = 1.f - fy1;
            float4 R0 = cb[m];
            float4 R1 = cb[m + 1];
            float4 R2 = cb[m + 2];
            // pixel i = acc[2p], pixel i+1 = acc[2p+1]
            acc[2*p][0]   = fmaf(R2.x, a2, fmaf(R1.x, a1, fmaf(R0.x, a0, acc[2*p][0])));
            acc[2*p][1]   = fmaf(R2.y, a2, fmaf(R1.y, a1, fmaf(R0.y, a0, acc[2*p][1])));
            acc[2*p][2]   = fmaf(R2.z, a2, fmaf(R1.z, a1, fmaf(R0.z, a0, acc[2*p][2])));
            acc[2*p][3]   = fmaf(R2.w, a2, fmaf(R1.w, a1, fmaf(R0.w, a0, acc[2*p][3])));
            acc[2*p+1][0] = fmaf(R1.x, fy1, fmaf(R0.x, b0, acc[2*p+1][0]));
            acc[2*p+1][1] = fmaf(R1.y, fy1, fmaf(R0.y, b0, acc[2*p+1][1]));
            acc[2*p+1][2] = fmaf(R1.z, fy1, fmaf(R0.z, b0, acc[2*p+1][2]));
            acc[2*p+1][3] = fmaf(R1.w, fy1, fmaf(R0.w, b0, acc[2*p+1][3]));
        }
        __syncthreads();   // reads of cur done; next DMA drained
        cur ^= 1;
    }

    float* part = parts + (size_t)chunk * CHUNK_ELEMS;
#pragma unroll
    for (int n = 0; n < 4; ++n)
#pragma unroll
        for (int u = 0; u < 8; ++u)
            part[(n * DD + (i0 + u)) * DD + j] = acc[u][n];
}

// ---------------- K3: reduce 12 chunks + scale (float4) ----------------
__global__ __launch_bounds__(256) void k_reduce(float* __restrict__ out,
                                                const float* __restrict__ ws) {
    int t = blockIdx.x * 256 + threadIdx.x;            // 262144 float4
    const float4* p = (const float4*)(ws + OFF_PART);
    const int C4 = CHUNK_ELEMS / 4;
    float4 a = p[t];
#pragma unroll
    for (int c = 1; c < NCHUNK; ++c) {
        float4 b = p[t + c * C4];
        a.x += b.x; a.y += b.y; a.z += b.z; a.w += b.w;
    }
    const float s = (float)(3.14159265358979323846 / 720.0);
    float4 r;
    r.x = a.x * s; r.y = a.y * s; r.z = a.z * s; r.w = a.w * s;
    ((float4*)out)[t] = r;
}

extern "C" void kernel_launch(void* const* d_in, const int* in_sizes, int n_in,
                              void* d_out, int out_size, void* d_ws, size_t ws_size,
                              hipStream_t stream) {
    const float* radon = (const float*)d_in[0];
    const float* hG    = (const float*)d_in[1];
    // d_in[2] (t_y, 377MB) intentionally unused: recomputed analytically.
    float* out = (float*)d_out;
    float* ws  = (float*)d_ws;

    k_transpose<<<dim3(12, 16, 4), dim3(32, 8), 0, stream>>>(radon, ws);
    k_filter<<<WW, 256, 0, stream>>>(hG, ws);
    k_backproj<<<dim3(8, 16, NCHUNK), 256, 0, stream>>>(ws, ws + OFF_PART);
    k_reduce<<<1024, 256, 0, stream>>>(out, ws);
}

// Round 8
// 109.376 us; speedup vs baseline: 1.0096x; 1.0096x over previous
//
#include <hip/hip_runtime.h>

#define HH 512        // sinogram height (H_IN)
#define WW 360        // angles (W_IN)
#define NB 4          // batch
#define DD 512        // output D

#define NCHUNK 12
#define ANG_PER 30                          // 360/12

#define FSTRIDE 768                         // float4 rows per angle: 128 zero | 512 data | 128 zero
#define FOFFS   128                         // data row offset within stride
#define NR      128                         // staged window rows (>= 74 + slack)

// ws layout in floats
#define OFF_TAB  0                          // float2 tab[360] -> 720 floats, pad to 1024
#define OFF_RT   1024                       // radonT [4][360][512] fp32
#define OFF_FILT (1024 + NB*WW*HH)          // filt_pad [361][768] float4 (last angle = DMA slack)
#define OFF_PART (OFF_FILT + (WW+1)*FSTRIDE*4)
#define CHUNK_ELEMS (NB*DD*DD)

#define GLOAD_LDS16(gp, lp)                                                   \
    __builtin_amdgcn_global_load_lds(                                         \
        (const __attribute__((address_space(1))) void*)(gp),                  \
        (__attribute__((address_space(3))) void*)(lp), 16, 0, 0)

// ---------------- K0: transpose radon[n][h][w] -> radonT[n][w][h] ----------------
__global__ __launch_bounds__(256) void k_transpose(const float* __restrict__ radon,
                                                   float* __restrict__ ws) {
    __shared__ float tile[32][33];
    int n  = blockIdx.z;
    int w0 = blockIdx.x * 32, h0 = blockIdx.y * 32;
    int x = threadIdx.x, y = threadIdx.y;  // 32 x 8
    const float* rn = radon + n * (HH * WW);
#pragma unroll
    for (int r = 0; r < 32; r += 8) {
        int h = h0 + y + r, w = w0 + x;
        tile[y + r][x] = (w < WW) ? rn[h * WW + w] : 0.f;
    }
    __syncthreads();
    float* rt = ws + OFF_RT + n * (WW * HH);
#pragma unroll
    for (int r = 0; r < 32; r += 8) {
        int w = w0 + y + r, h = h0 + x;
        if (w < WW) rt[w * HH + h] = tile[x][y + r];
    }
}

// ---------------- K1: circular ramp filter + angle table + zero pads ----------------
// filt_pad[wA][FOFFS + y] = float4{ v_n(y) }, rows [0,128) and [640,768) zeroed.
__global__ __launch_bounds__(256) void k_filter(const float* __restrict__ hG,
                                                float* __restrict__ ws) {
    __shared__ float r2[NB][1024];          // r2[n][i] = col[(i+257)&511]
    int wA  = blockIdx.x;
    int tid = threadIdx.x;

    if (tid == 0) {                          // angle table (double trig, validated)
        double th = (3.14159265358979323846 / 180.0) * (0.5 * (double)wA);
        double c = cos(th), s = sin(th);
        float2 ab;
        ab.x = (float)(c * (255.5 / 256.0));
        ab.y = (float)(-s * (255.5 / 256.0));
        ((float2*)(ws + OFF_TAB))[wA] = ab;
    }
    {   // zero pad rows
        float4* fp = (float4*)(ws + OFF_FILT) + (size_t)wA * FSTRIDE;
        float4 z = make_float4(0.f, 0.f, 0.f, 0.f);
        if (tid < 128) { fp[tid] = z; fp[640 + tid] = z; }
    }

    const float* rt = ws + OFF_RT;
    for (int t = tid; t < NB * 1024; t += 256) {
        int n = t >> 10, i = t & 1023;
        r2[n][i] = rt[(n * WW + wA) * HH + ((i + 257) & 511)];
    }
    __syncthreads();

    int n = tid >> 6, lane = tid & 63, y0 = lane << 3;   // 8 consecutive y per thread
    float acc[8] = {0, 0, 0, 0, 0, 0, 0, 0};
    const float* rr = &r2[n][y0];
    float4 Wr0 = *(const float4*)(rr + 0);
    float4 Wr1 = *(const float4*)(rr + 4);
    float4 Wr2 = *(const float4*)(rr + 8);
    float4 Wr3 = *(const float4*)(rr + 12);

    for (int d = 0; d < 512; d += 8) {
        float hg[8];
#pragma unroll
        for (int q = 0; q < 8; ++q) hg[q] = hG[d + q];   // uniform -> s_load
        float wf[16] = {Wr0.x, Wr0.y, Wr0.z, Wr0.w, Wr1.x, Wr1.y, Wr1.z, Wr1.w,
                        Wr2.x, Wr2.y, Wr2.z, Wr2.w, Wr3.x, Wr3.y, Wr3.z, Wr3.w};
#pragma unroll
        for (int du = 0; du < 8; ++du)
#pragma unroll
            for (int u = 0; u < 8; ++u)
                acc[u] = fmaf(wf[du + u], hg[du], acc[u]);
        if (d < 504) {
            Wr0 = Wr2; Wr1 = Wr3;
            Wr2 = *(const float4*)(rr + d + 16);
            Wr3 = *(const float4*)(rr + d + 20);
        }
    }
    float* filt = ws + OFF_FILT;
#pragma unroll
    for (int u = 0; u < 8; ++u)
        filt[((size_t)wA * FSTRIDE + FOFFS + y0 + u) * 4 + n] = acc[u];
}

// ---------------- K2: backprojection, windowed 128-row staging ----------------
// Per (block, angle): only rows [base, base+128) are staged (2KB), where
// base = floor(min_corner py) - 2.  Corner min bounds all lattice lanes
// (fp32 fma monotone per argument).  Zero boundary rows come pre-padded
// in filt_pad, so the DMA is unpredicated and gathers need no clamps.
__global__ __launch_bounds__(256, 6) void k_backproj(const float* __restrict__ ws,
                                                     float* __restrict__ parts) {
    __shared__ float4 buf[2][NR];
    const int tid   = threadIdx.x;
    const int lane  = tid & 63;
    const int ithr  = tid >> 6;                        // 0..3
    const int j     = blockIdx.x * 64 + lane;
    const int i0    = blockIdx.y * 32 + ithr;          // i = i0 + 4u, u<8
    const int chunk = blockIdx.z;

    const float2* tab = (const float2*)(ws + OFF_TAB);
    const float4* fd  = (const float4*)(ws + OFF_FILT);

    float acc[8][4];
#pragma unroll
    for (int u = 0; u < 8; ++u)
#pragma unroll
        for (int n = 0; n < 4; ++n) acc[u][n] = 0.f;

    float jf = (float)(j - 256);
    float ifl[8];
#pragma unroll
    for (int u = 0; u < 8; ++u) ifl[u] = (float)(i0 + 4 * u - 256);

    // tile corner coordinates (uniform per block)
    const float jlo = (float)((int)blockIdx.x * 64 - 256);
    const float jhi = (float)((int)blockIdx.x * 64 + 63 - 256);
    const float ilo = (float)((int)blockIdx.y * 32 - 256);
    const float ihi = (float)((int)blockIdx.y * 32 + 31 - 256);

    const int wbeg = chunk * ANG_PER;
    float2 abc = tab[wbeg];
    float2 abn = tab[wbeg + 1];

    float basefc;
    {
        float t = fminf(fmaf(abc.x, jlo, 255.5f), fmaf(abc.x, jhi, 255.5f));
        float pymin = fminf(fmaf(abc.y, ilo, t), fmaf(abc.y, ihi, t));
        basefc = floorf(pymin) - 2.0f;
    }
    if (tid < NR)   // waves 0,1 fully active: linear lane->LDS dest preserved
        GLOAD_LDS16(fd + (size_t)wbeg * FSTRIDE + (FOFFS + (int)basefc + tid),
                    &buf[0][tid]);
    __syncthreads();   // vmcnt(0) drain: window resident

    int cur = 0;
    for (int k = 0; k < ANG_PER; ++k) {
        const int w = wbeg + k;
        float2 abn2 = tab[min(w + 2, WW - 1)];         // prefetch 2 ahead (uniform)
        float basefn = 0.f;
        if (k + 1 < ANG_PER) {                         // stage next window
            float t = fminf(fmaf(abn.x, jlo, 255.5f), fmaf(abn.x, jhi, 255.5f));
            float pymin = fminf(fmaf(abn.y, ilo, t), fmaf(abn.y, ihi, t));
            basefn = floorf(pymin) - 2.0f;
            if (tid < NR)
                GLOAD_LDS16(fd + (size_t)(w + 1) * FSTRIDE + (FOFFS + (int)basefn + tid),
                            &buf[cur ^ 1][tid]);
        }

        float pybase = fmaf(abc.x, jf, 255.5f);
        const float4* cb = buf[cur];
#pragma unroll
        for (int u = 0; u < 8; ++u) {
            float pya = fmaf(abc.y, ifl[u], pybase);   // absolute py (same as R6)
            float pyr = pya - basefc;                  // exact fp32 sub; in [2, 76)
            float cf  = truncf(pyr);
            float fy  = pyr - cf;
            int   c   = (int)cf;
            float4 p0 = cb[c];
            float4 p1 = cb[c + 1];
            float w0  = 1.f - fy;
            acc[u][0] = fmaf(p1.x, fy, fmaf(p0.x, w0, acc[u][0]));
            acc[u][1] = fmaf(p1.y, fy, fmaf(p0.y, w0, acc[u][1]));
            acc[u][2] = fmaf(p1.z, fy, fmaf(p0.z, w0, acc[u][2]));
            acc[u][3] = fmaf(p1.w, fy, fmaf(p0.w, w0, acc[u][3]));
        }
        __syncthreads();   // reads of cur done; next window's DMA drained
        abc = abn; abn = abn2; basefc = basefn; cur ^= 1;
    }

    float* part = parts + (size_t)chunk * CHUNK_ELEMS;
#pragma unroll
    for (int n = 0; n < 4; ++n)
#pragma unroll
        for (int u = 0; u < 8; ++u)
            part[(n * DD + (i0 + 4 * u)) * DD + j] = acc[u][n];
}

// ---------------- K3: reduce 12 chunks + scale (float4) ----------------
__global__ __launch_bounds__(256) void k_reduce(float* __restrict__ out,
                                                const float* __restrict__ ws) {
    int t = blockIdx.x * 256 + threadIdx.x;            // 262144 float4
    const float4* p = (const float4*)(ws + OFF_PART);
    const int C4 = CHUNK_ELEMS / 4;
    float4 a = p[t];
#pragma unroll
    for (int c = 1; c < NCHUNK; ++c) {
        float4 b = p[t + c * C4];
        a.x += b.x; a.y += b.y; a.z += b.z; a.w += b.w;
    }
    const float s = (float)(3.14159265358979323846 / 720.0);
    float4 r;
    r.x = a.x * s; r.y = a.y * s; r.z = a.z * s; r.w = a.w * s;
    ((float4*)out)[t] = r;
}

extern "C" void kernel_launch(void* const* d_in, const int* in_sizes, int n_in,
                              void* d_out, int out_size, void* d_ws, size_t ws_size,
                              hipStream_t stream) {
    const float* radon = (const float*)d_in[0];
    const float* hG    = (const float*)d_in[1];
    // d_in[2] (t_y, 377MB) intentionally unused: recomputed analytically.
    float* out = (float*)d_out;
    float* ws  = (float*)d_ws;

    k_transpose<<<dim3(12, 16, 4), dim3(32, 8), 0, stream>>>(radon, ws);
    k_filter<<<WW, 256, 0, stream>>>(hG, ws);
    k_backproj<<<dim3(8, 16, NCHUNK), 256, 0, stream>>>(ws, ws + OFF_PART);
    k_reduce<<<1024, 256, 0, stream>>>(out, ws);
}

// Round 9
// 108.190 us; speedup vs baseline: 1.0207x; 1.0110x over previous
//
#include <hip/hip_runtime.h>

#define HH 512        // sinogram height (H_IN)
#define WW 360        // angles (W_IN)
#define NB 4          // batch
#define DD 512        // output D

#define NCHUNK 12
#define ANG_PER 30                          // 360/12

#define FSTRIDE 768                         // float4 rows per angle: 128 zero | 512 data | 128 zero
#define FOFFS   128                         // data row offset within stride
#define NR      128                         // staged window rows (span <= 75 + slack)

// ws layout in floats
#define OFF_TAB  0                          // float2 tab[360] -> 720 floats, pad to 1024
#define OFF_RT   1024                       // radonT [4][360][512] fp32
#define OFF_FILT (1024 + NB*WW*HH)          // filt_pad [361][768] float4
#define OFF_PART (OFF_FILT + (WW+1)*FSTRIDE*4)
#define CHUNK_ELEMS (NB*DD*DD)

#define GLOAD_LDS16(gp, lp)                                                   \
    __builtin_amdgcn_global_load_lds(                                         \
        (const __attribute__((address_space(1))) void*)(gp),                  \
        (__attribute__((address_space(3))) void*)(lp), 16, 0, 0)

// ---------------- K0: transpose radon[n][h][w] -> radonT[n][w][h] ----------------
__global__ __launch_bounds__(256) void k_transpose(const float* __restrict__ radon,
                                                   float* __restrict__ ws) {
    __shared__ float tile[32][33];
    int n  = blockIdx.z;
    int w0 = blockIdx.x * 32, h0 = blockIdx.y * 32;
    int x = threadIdx.x, y = threadIdx.y;  // 32 x 8
    const float* rn = radon + n * (HH * WW);
#pragma unroll
    for (int r = 0; r < 32; r += 8) {
        int h = h0 + y + r, w = w0 + x;
        tile[y + r][x] = (w < WW) ? rn[h * WW + w] : 0.f;
    }
    __syncthreads();
    float* rt = ws + OFF_RT + n * (WW * HH);
#pragma unroll
    for (int r = 0; r < 32; r += 8) {
        int w = w0 + y + r, h = h0 + x;
        if (w < WW) rt[w * HH + h] = tile[x][y + r];
    }
}

// ---------------- K1: circular ramp filter + angle table + zero pads ----------------
// filt_pad[wA][FOFFS + y] = float4{ v_n(y) }, rows [0,128) and [640,768) zeroed.
__global__ __launch_bounds__(256) void k_filter(const float* __restrict__ hG,
                                                float* __restrict__ ws) {
    __shared__ float r2[NB][1024];          // r2[n][i] = col[(i+257)&511]
    int wA  = blockIdx.x;
    int tid = threadIdx.x;

    if (tid == 0) {                          // angle table (double trig, validated)
        double th = (3.14159265358979323846 / 180.0) * (0.5 * (double)wA);
        double c = cos(th), s = sin(th);
        float2 ab;
        ab.x = (float)(c * (255.5 / 256.0));
        ab.y = (float)(-s * (255.5 / 256.0));
        ((float2*)(ws + OFF_TAB))[wA] = ab;
    }
    {   // zero pad rows
        float4* fp = (float4*)(ws + OFF_FILT) + (size_t)wA * FSTRIDE;
        float4 z = make_float4(0.f, 0.f, 0.f, 0.f);
        if (tid < 128) { fp[tid] = z; fp[640 + tid] = z; }
    }

    const float* rt = ws + OFF_RT;
    for (int t = tid; t < NB * 1024; t += 256) {
        int n = t >> 10, i = t & 1023;
        r2[n][i] = rt[(n * WW + wA) * HH + ((i + 257) & 511)];
    }
    __syncthreads();

    int n = tid >> 6, lane = tid & 63, y0 = lane << 3;   // 8 consecutive y per thread
    float acc[8] = {0, 0, 0, 0, 0, 0, 0, 0};
    const float* rr = &r2[n][y0];
    float4 Wr0 = *(const float4*)(rr + 0);
    float4 Wr1 = *(const float4*)(rr + 4);
    float4 Wr2 = *(const float4*)(rr + 8);
    float4 Wr3 = *(const float4*)(rr + 12);

    for (int d = 0; d < 512; d += 8) {
        float hg[8];
#pragma unroll
        for (int q = 0; q < 8; ++q) hg[q] = hG[d + q];   // uniform -> s_load
        float wf[16] = {Wr0.x, Wr0.y, Wr0.z, Wr0.w, Wr1.x, Wr1.y, Wr1.z, Wr1.w,
                        Wr2.x, Wr2.y, Wr2.z, Wr2.w, Wr3.x, Wr3.y, Wr3.z, Wr3.w};
#pragma unroll
        for (int du = 0; du < 8; ++du)
#pragma unroll
            for (int u = 0; u < 8; ++u)
                acc[u] = fmaf(wf[du + u], hg[du], acc[u]);
        if (d < 504) {
            Wr0 = Wr2; Wr1 = Wr3;
            Wr2 = *(const float4*)(rr + d + 16);
            Wr3 = *(const float4*)(rr + d + 20);
        }
    }
    float* filt = ws + OFF_FILT;
#pragma unroll
    for (int u = 0; u < 8; ++u)
        filt[((size_t)wA * FSTRIDE + FOFFS + y0 + u) * 4 + n] = acc[u];
}

// ---------------- K2: backprojection, depth-3 counted-vmcnt pipeline ----------------
// 4 rotating 2KB window buffers.  DMA(k) issued 3 iterations before compute(k);
// every barrier is raw s_barrier preceded by s_waitcnt vmcnt(2) (never 0 in-loop),
// so 3 windows stay in flight and the drain stall vanishes (T3/T4).
__global__ __launch_bounds__(256, 6) void k_backproj(const float* __restrict__ ws,
                                                     float* __restrict__ parts) {
    __shared__ float4 buf[4][NR];           // 8 KB rotating windows
    __shared__ float2 tl[ANG_PER];          // this chunk's angle table
    const int tid   = threadIdx.x;
    const int lane  = tid & 63;
    const int ithr  = tid >> 6;             // 0..3
    const int j     = blockIdx.x * 64 + lane;
    const int i0    = blockIdx.y * 32 + ithr;   // i = i0 + 4u, u<8
    const int chunk = blockIdx.z;
    const int wbeg  = chunk * ANG_PER;

    const float2* tab = (const float2*)(ws + OFF_TAB);
    const float4* fd  = (const float4*)(ws + OFF_FILT);

    if (tid < ANG_PER) tl[tid] = tab[wbeg + tid];
    __syncthreads();                        // tab resident; vmcnt drained (no DMAs yet)

    float acc[8][4];
#pragma unroll
    for (int u = 0; u < 8; ++u)
#pragma unroll
        for (int n = 0; n < 4; ++n) acc[u][n] = 0.f;

    float jf = (float)(j - 256);
    float ifl[8];
#pragma unroll
    for (int u = 0; u < 8; ++u) ifl[u] = (float)(i0 + 4 * u - 256);

    // tile corner coordinates (uniform per block); fp32 fma monotone per arg
    const float jlo = (float)((int)blockIdx.x * 64 - 256);
    const float jhi = (float)((int)blockIdx.x * 64 + 63 - 256);
    const float ilo = (float)((int)blockIdx.y * 32 - 256);
    const float ihi = (float)((int)blockIdx.y * 32 + 31 - 256);

#define CALC_BASE(ab, dst)                                                    \
    {                                                                         \
        float t_ = fminf(fmaf((ab).x, jlo, 255.5f), fmaf((ab).x, jhi, 255.5f)); \
        float pm_ = fminf(fmaf((ab).y, ilo, t_), fmaf((ab).y, ihi, t_));      \
        (dst) = floorf(pm_) - 2.0f;                                           \
    }

    float2 abA = tl[0], abB = tl[1], abC = tl[2], abD;
    float bA, bB, bC, bD;
    CALC_BASE(abA, bA); CALC_BASE(abB, bB); CALC_BASE(abC, bC);

    if (tid < NR) {   // waves 0,1 fully active: linear lane->LDS dest preserved
        GLOAD_LDS16(fd + (size_t)(wbeg + 0) * FSTRIDE + (FOFFS + (int)bA + tid), &buf[0][tid]);
        GLOAD_LDS16(fd + (size_t)(wbeg + 1) * FSTRIDE + (FOFFS + (int)bB + tid), &buf[1][tid]);
        GLOAD_LDS16(fd + (size_t)(wbeg + 2) * FSTRIDE + (FOFFS + (int)bC + tid), &buf[2][tid]);
    }
    asm volatile("s_waitcnt vmcnt(2)" ::: "memory");   // DMA(0) retired
    __builtin_amdgcn_s_barrier();
    __builtin_amdgcn_sched_barrier(0);

    for (int k = 0; k < ANG_PER; ++k) {
        {   // issue DMA for angle k+3 (tail: redirect to a valid, never-read window)
            bool ok  = (k + 3 < ANG_PER);
            int  idx = ok ? (k + 3) : 0;
            abD = tl[idx];
            if (ok) { CALC_BASE(abD, bD); } else { bD = 0.0f; }
            int wsrc = ok ? (wbeg + k + 3) : wbeg;
            if (tid < NR)
                GLOAD_LDS16(fd + (size_t)wsrc * FSTRIDE + (FOFFS + (int)bD + tid),
                            &buf[(k + 3) & 3][tid]);
        }

        // compute angle k from buf[k&3] (DMA retired by previous iteration's wait)
        float pybase = fmaf(abA.x, jf, 255.5f);
        const float4* cb = buf[k & 3];
#pragma unroll
        for (int u = 0; u < 8; ++u) {
            float pya = fmaf(abA.y, ifl[u], pybase);   // absolute py
            float pyr = pya - bA;                      // exact fp32 sub; in [2, 77)
            float cf  = truncf(pyr);
            float fy  = pyr - cf;
            int   c   = (int)cf;
            float4 p0 = cb[c];
            float4 p1 = cb[c + 1];
            float w0  = 1.f - fy;
            acc[u][0] = fmaf(p1.x, fy, fmaf(p0.x, w0, acc[u][0]));
            acc[u][1] = fmaf(p1.y, fy, fmaf(p0.y, w0, acc[u][1]));
            acc[u][2] = fmaf(p1.z, fy, fmaf(p0.z, w0, acc[u][2]));
            acc[u][3] = fmaf(p1.w, fy, fmaf(p0.w, w0, acc[u][3]));
        }

        asm volatile("s_waitcnt vmcnt(2)" ::: "memory");  // retire oldest (angle k+1)
        __builtin_amdgcn_s_barrier();
        __builtin_amdgcn_sched_barrier(0);

        abA = abB; abB = abC; abC = abD;
        bA  = bB;  bB  = bC;  bC  = bD;
    }

    asm volatile("s_waitcnt vmcnt(0)" ::: "memory");   // drain tail DMAs before LDS retire

    float* part = parts + (size_t)chunk * CHUNK_ELEMS;
#pragma unroll
    for (int n = 0; n < 4; ++n)
#pragma unroll
        for (int u = 0; u < 8; ++u)
            part[(n * DD + (i0 + 4 * u)) * DD + j] = acc[u][n];
#undef CALC_BASE
}

// ---------------- K3: reduce 12 chunks + scale (float4) ----------------
__global__ __launch_bounds__(256) void k_reduce(float* __restrict__ out,
                                                const float* __restrict__ ws) {
    int t = blockIdx.x * 256 + threadIdx.x;            // 262144 float4
    const float4* p = (const float4*)(ws + OFF_PART);
    const int C4 = CHUNK_ELEMS / 4;
    float4 a = p[t];
#pragma unroll
    for (int c = 1; c < NCHUNK; ++c) {
        float4 b = p[t + c * C4];
        a.x += b.x; a.y += b.y; a.z += b.z; a.w += b.w;
    }
    const float s = (float)(3.14159265358979323846 / 720.0);
    float4 r;
    r.x = a.x * s; r.y = a.y * s; r.z = a.z * s; r.w = a.w * s;
    ((float4*)out)[t] = r;
}

extern "C" void kernel_launch(void* const* d_in, const int* in_sizes, int n_in,
                              void* d_out, int out_size, void* d_ws, size_t ws_size,
                              hipStream_t stream) {
    const float* radon = (const float*)d_in[0];
    const float* hG    = (const float*)d_in[1];
    // d_in[2] (t_y, 377MB) intentionally unused: recomputed analytically.
    float* out = (float*)d_out;
    float* ws  = (float*)d_ws;

    k_transpose<<<dim3(12, 16, 4), dim3(32, 8), 0, stream>>>(radon, ws);
    k_filter<<<WW, 256, 0, stream>>>(hG, ws);
    k_backproj<<<dim3(8, 16, NCHUNK), 256, 0, stream>>>(ws, ws + OFF_PART);
    k_reduce<<<1024, 256, 0, stream>>>(out, ws);
}

// Round 10
// 108.087 us; speedup vs baseline: 1.0217x; 1.0010x over previous
//
#include <hip/hip_runtime.h>

#define HH 512        // sinogram height (H_IN)
#define WW 360        // angles (W_IN)
#define NB 4          // batch
#define DD 512        // output D

#define NCHUNK 6
#define ANG_PER 60                          // 360/6

#define FSTRIDE 768                         // float4 rows per angle: 128 zero | 512 data | 128 zero
#define FOFFS   128                         // data row offset within stride
#define NR      128                         // staged window rows (span <= 97 + slack)

// ws layout in floats
#define OFF_TAB  0                          // float2 tab[360] -> 1024 floats
#define OFF_FILT 1024                       // filt_pad [361][768] float4
#define OFF_PART (OFF_FILT + (WW+1)*FSTRIDE*4)  // parts [6][512*512] float4
#define PIX (DD*DD)

#define GLOAD_LDS16(gp, lp)                                                   \
    __builtin_amdgcn_global_load_lds(                                         \
        (const __attribute__((address_space(1))) void*)(gp),                  \
        (__attribute__((address_space(3))) void*)(lp), 16, 0, 0)

// ---------------- K1: fused transpose + circular ramp filter ----------------
// r2[n][i] = radon[n][(i+257)&511][wA]  (strided loads, radon is L2-resident)
// filt_pad[wA][FOFFS+y] = float4{ v_n(y) }, rows [0,128) and [640,768) zeroed.
__global__ __launch_bounds__(256) void k_filter(const float* __restrict__ radon,
                                                const float* __restrict__ hG,
                                                float* __restrict__ ws) {
    __shared__ float r2[NB][1024];          // duplicated circular span
    int wA  = blockIdx.x;
    int tid = threadIdx.x;

    if (tid == 0) {                          // angle table (double trig, validated)
        double th = (3.14159265358979323846 / 180.0) * (0.5 * (double)wA);
        double c = cos(th), s = sin(th);
        float2 ab;
        ab.x = (float)(c * (255.5 / 256.0));
        ab.y = (float)(-s * (255.5 / 256.0));
        ((float2*)(ws + OFF_TAB))[wA] = ab;
    }
    {   // zero pad rows of this angle's filt slot
        float4* fp = (float4*)(ws + OFF_FILT) + (size_t)wA * FSTRIDE;
        float4 z = make_float4(0.f, 0.f, 0.f, 0.f);
        if (tid < 128) { fp[tid] = z; fp[640 + tid] = z; }
    }

    // fused transpose: 16 strided loads per thread
    for (int t = tid; t < NB * 1024; t += 256) {
        int n = t >> 10, i = t & 1023;
        int h = (i + 257) & 511;
        r2[n][i] = radon[((size_t)(n * HH + h)) * WW + wA];
    }
    __syncthreads();

    int n = tid >> 6, lane = tid & 63, y0 = lane << 3;   // 8 consecutive y per thread
    float acc[8] = {0, 0, 0, 0, 0, 0, 0, 0};
    const float* rr = &r2[n][y0];
    float4 Wr0 = *(const float4*)(rr + 0);
    float4 Wr1 = *(const float4*)(rr + 4);
    float4 Wr2 = *(const float4*)(rr + 8);
    float4 Wr3 = *(const float4*)(rr + 12);

    for (int d = 0; d < 512; d += 8) {
        float hg[8];
#pragma unroll
        for (int q = 0; q < 8; ++q) hg[q] = hG[d + q];   // uniform -> s_load
        float wf[16] = {Wr0.x, Wr0.y, Wr0.z, Wr0.w, Wr1.x, Wr1.y, Wr1.z, Wr1.w,
                        Wr2.x, Wr2.y, Wr2.z, Wr2.w, Wr3.x, Wr3.y, Wr3.z, Wr3.w};
#pragma unroll
        for (int du = 0; du < 8; ++du)
#pragma unroll
            for (int u = 0; u < 8; ++u)
                acc[u] = fmaf(wf[du + u], hg[du], acc[u]);
        if (d < 504) {
            Wr0 = Wr2; Wr1 = Wr3;
            Wr2 = *(const float4*)(rr + d + 16);
            Wr3 = *(const float4*)(rr + d + 20);
        }
    }
    float* filt = ws + OFF_FILT;
#pragma unroll
    for (int u = 0; u < 8; ++u)
        filt[((size_t)wA * FSTRIDE + FOFFS + y0 + u) * 4 + n] = acc[u];
}

// ---------------- K2: backprojection, depth-3 counted-vmcnt pipeline ----------------
// NCHUNK=6 (60 angles/block, 3 blocks/CU); 4 rotating 2KB window buffers.
// DMA(k) issued 3 iterations ahead; s_waitcnt vmcnt(2) + raw s_barrier per angle.
__global__ __launch_bounds__(256, 3) void k_backproj(const float* __restrict__ ws,
                                                     float* __restrict__ parts) {
    __shared__ float4 buf[4][NR];           // 8 KB rotating windows
    __shared__ float2 tl[ANG_PER];          // this chunk's angle table
    const int tid   = threadIdx.x;
    const int lane  = tid & 63;
    const int ithr  = tid >> 6;             // 0..3
    const int j     = blockIdx.x * 64 + lane;
    const int i0    = blockIdx.y * 32 + ithr;   // i = i0 + 4u, u<8
    const int chunk = blockIdx.z;
    const int wbeg  = chunk * ANG_PER;

    const float2* tab = (const float2*)(ws + OFF_TAB);
    const float4* fd  = (const float4*)(ws + OFF_FILT);

    if (tid < ANG_PER) tl[tid] = tab[wbeg + tid];
    __syncthreads();                        // tab resident; vmcnt drained (no DMAs yet)

    float acc[8][4];
#pragma unroll
    for (int u = 0; u < 8; ++u)
#pragma unroll
        for (int n = 0; n < 4; ++n) acc[u][n] = 0.f;

    float jf = (float)(j - 256);
    float ifl[8];
#pragma unroll
    for (int u = 0; u < 8; ++u) ifl[u] = (float)(i0 + 4 * u - 256);

    // tile corner coordinates (uniform per block); fp32 fma monotone per arg
    const float jlo = (float)((int)blockIdx.x * 64 - 256);
    const float jhi = (float)((int)blockIdx.x * 64 + 63 - 256);
    const float ilo = (float)((int)blockIdx.y * 32 - 256);
    const float ihi = (float)((int)blockIdx.y * 32 + 31 - 256);

#define CALC_BASE(ab, dst)                                                    \
    {                                                                         \
        float t_ = fminf(fmaf((ab).x, jlo, 255.5f), fmaf((ab).x, jhi, 255.5f)); \
        float pm_ = fminf(fmaf((ab).y, ilo, t_), fmaf((ab).y, ihi, t_));      \
        (dst) = floorf(pm_) - 2.0f;                                           \
    }

    float2 abA = tl[0], abB = tl[1], abC = tl[2], abD;
    float bA, bB, bC, bD;
    CALC_BASE(abA, bA); CALC_BASE(abB, bB); CALC_BASE(abC, bC);

    if (tid < NR) {   // waves 0,1 fully active: linear lane->LDS dest preserved
        GLOAD_LDS16(fd + (size_t)(wbeg + 0) * FSTRIDE + (FOFFS + (int)bA + tid), &buf[0][tid]);
        GLOAD_LDS16(fd + (size_t)(wbeg + 1) * FSTRIDE + (FOFFS + (int)bB + tid), &buf[1][tid]);
        GLOAD_LDS16(fd + (size_t)(wbeg + 2) * FSTRIDE + (FOFFS + (int)bC + tid), &buf[2][tid]);
    }
    asm volatile("s_waitcnt vmcnt(2)" ::: "memory");   // DMA(0) retired
    __builtin_amdgcn_s_barrier();
    __builtin_amdgcn_sched_barrier(0);

    for (int k = 0; k < ANG_PER; ++k) {
        {   // issue DMA for angle k+3 (tail: redirect to valid, never-read window)
            bool ok  = (k + 3 < ANG_PER);
            int  idx = ok ? (k + 3) : 0;
            abD = tl[idx];
            if (ok) { CALC_BASE(abD, bD); } else { bD = 0.0f; }
            int wsrc = ok ? (wbeg + k + 3) : wbeg;
            if (tid < NR)
                GLOAD_LDS16(fd + (size_t)wsrc * FSTRIDE + (FOFFS + (int)bD + tid),
                            &buf[(k + 3) & 3][tid]);
        }

        // compute angle k from buf[k&3]
        float pybase = fmaf(abA.x, jf, 255.5f);
        const float4* cb = buf[k & 3];
#pragma unroll
        for (int u = 0; u < 8; ++u) {
            float pya = fmaf(abA.y, ifl[u], pybase);   // absolute py
            float pyr = pya - bA;                      // exact fp32 sub
            float cf  = truncf(pyr);
            float fy  = pyr - cf;
            int   c   = (int)cf;
            float4 p0 = cb[c];
            float4 p1 = cb[c + 1];
            float w0  = 1.f - fy;
            acc[u][0] = fmaf(p1.x, fy, fmaf(p0.x, w0, acc[u][0]));
            acc[u][1] = fmaf(p1.y, fy, fmaf(p0.y, w0, acc[u][1]));
            acc[u][2] = fmaf(p1.z, fy, fmaf(p0.z, w0, acc[u][2]));
            acc[u][3] = fmaf(p1.w, fy, fmaf(p0.w, w0, acc[u][3]));
        }

        asm volatile("s_waitcnt vmcnt(2)" ::: "memory");  // retire oldest
        __builtin_amdgcn_s_barrier();
        __builtin_amdgcn_sched_barrier(0);

        abA = abB; abB = abC; abC = abD;
        bA  = bB;  bB  = bC;  bC  = bD;
    }

    asm volatile("s_waitcnt vmcnt(0)" ::: "memory");   // drain tail DMAs

    // parts layout: [chunk][i*512+j] float4 over n -> 1KB/wave coalesced stores
    float4* p4 = (float4*)parts + (size_t)chunk * PIX;
#pragma unroll
    for (int u = 0; u < 8; ++u)
        p4[(size_t)(i0 + 4 * u) * DD + j] =
            make_float4(acc[u][0], acc[u][1], acc[u][2], acc[u][3]);
#undef CALC_BASE
}

// ---------------- K3: reduce 6 chunks + scale + transpose n out ----------------
__global__ __launch_bounds__(256) void k_reduce(float* __restrict__ out,
                                                const float* __restrict__ ws) {
    int t = blockIdx.x * 256 + threadIdx.x;            // 262144 pixels
    const float4* p = (const float4*)(ws + OFF_PART);
    float4 a = p[t];
#pragma unroll
    for (int c = 1; c < NCHUNK; ++c) {
        float4 b = p[(size_t)c * PIX + t];
        a.x += b.x; a.y += b.y; a.z += b.z; a.w += b.w;
    }
    const float s = (float)(3.14159265358979323846 / 720.0);
    out[t]           = a.x * s;
    out[PIX + t]     = a.y * s;
    out[2 * PIX + t] = a.z * s;
    out[3 * PIX + t] = a.w * s;
}

extern "C" void kernel_launch(void* const* d_in, const int* in_sizes, int n_in,
                              void* d_out, int out_size, void* d_ws, size_t ws_size,
                              hipStream_t stream) {
    const float* radon = (const float*)d_in[0];
    const float* hG    = (const float*)d_in[1];
    // d_in[2] (t_y, 377MB) intentionally unused: recomputed analytically.
    float* out = (float*)d_out;
    float* ws  = (float*)d_ws;

    k_filter<<<WW, 256, 0, stream>>>(radon, hG, ws);
    k_backproj<<<dim3(8, 16, NCHUNK), 256, 0, stream>>>(ws, ws + OFF_PART);
    k_reduce<<<1024, 256, 0, stream>>>(out, ws);
}